// Round 6
// baseline (1169.816 us; speedup 1.0000x reference)
//
#include <hip/hip_runtime.h>

// Problem constants: Q,K,V (4,8,1024,64) f32.
#define SCALE 0.125f

// ws layout (float offsets) — trig tables no longer materialized
//  FQ:   0          (2097152)   FK: 2097152
//  T:    6815744    (4 x 2097152 = 8388608)  [dead after stage2]
//  Qp:   6815744 (overlays T)   Kp: 15204352
#define WS_FLOATS_NEEDED 23592960ull

#define TWO_PI_OVER_512  0.012271846303085129f
#define TWO_PI_OVER_1024 0.0061359231517425646f

// ---------------- stage1: Tc += X*CN, Ts += X*SN, cols 0..319, K-split x2
// B-side trig generated in-register: CN[k][n] = cos(2pi*((k*n)&511)/512)
__global__ __launch_bounds__(256) void stage1_fused(
        const float* __restrict__ Qg, const float* __restrict__ Kg,
        float* __restrict__ TcQ, float* __restrict__ TsQ,
        float* __restrict__ TcK, float* __restrict__ TsK) {
    int bid = blockIdx.x;
    int xcd = bid & 7;
    int z = xcd >> 1;                        // inp*2 + kh
    int w = ((bid >> 3) << 1) | (xcd & 1);   // [0,320)
    int inp = z >> 1, kh = z & 1;
    int n0 = (w % 5) * 64, m0 = (w / 5) * 64;
    const float* X = inp ? Kg : Qg;
    float* Tc = inp ? TcK : TcQ;
    float* Ts = inp ? TsK : TsQ;
    __shared__ float At[16][68];                  // [kk][m]
    __shared__ float Bc[16][68], Bs[16][68];      // [kk][n]
    int tn = threadIdx.x & 15, tm = threadIdx.x >> 4;
    int mA = threadIdx.x >> 2, kqA = threadIdx.x & 3;
    int colB = threadIdx.x & 63, rowB = threadIdx.x >> 6;
    float accC[4][4] = {}, accS[4][4] = {};
    int kbeg = kh * 256;
    for (int k0 = kbeg; k0 < kbeg + 256; k0 += 16) {
        float4 va = *(const float4*)&X[(size_t)(m0 + mA) * 512 + k0 + 4 * kqA];
        At[4 * kqA + 0][mA] = va.x; At[4 * kqA + 1][mA] = va.y;
        At[4 * kqA + 2][mA] = va.z; At[4 * kqA + 3][mA] = va.w;
#pragma unroll
        for (int r = 0; r < 4; r++) {
            int krow = k0 + rowB + 4 * r;
            int ncol = n0 + colB;
            int t = (krow * ncol) & 511;
            float ang = (float)t * TWO_PI_OVER_512;
            Bc[rowB + 4 * r][colB] = __cosf(ang);
            Bs[rowB + 4 * r][colB] = __sinf(ang);
        }
        __syncthreads();
#pragma unroll
        for (int kk = 0; kk < 16; kk++) {
            float4 a  = *(const float4*)&At[kk][tm * 4];
            float4 bc = *(const float4*)&Bc[kk][tn * 4];
            float4 bs = *(const float4*)&Bs[kk][tn * 4];
            float av[4]  = {a.x, a.y, a.z, a.w};
            float bcv[4] = {bc.x, bc.y, bc.z, bc.w};
            float bsv[4] = {bs.x, bs.y, bs.z, bs.w};
#pragma unroll
            for (int i = 0; i < 4; i++)
#pragma unroll
                for (int j = 0; j < 4; j++) {
                    accC[i][j] += av[i] * bcv[j];
                    accS[i][j] += av[i] * bsv[j];
                }
        }
        __syncthreads();
    }
#pragma unroll
    for (int i = 0; i < 4; i++) {
        size_t rbase = (size_t)(m0 + tm * 4 + i) * 512 + n0 + tn * 4;
#pragma unroll
        for (int j = 0; j < 4; j++) {
            atomicAdd(&Tc[rbase + j], accC[i][j]);
            atomicAdd(&Ts[rbase + j], accS[i][j]);
        }
    }
}

// ---------------- stage2: F += CM*Tc - SM*Ts, cols 0..319, K-split x4
// A-side trig generated in-register: CM[m][k] = cos(2pi*((m*k)&1023)/1024)
__global__ __launch_bounds__(256) void stage2_fused(
        const float* __restrict__ TcQ, const float* __restrict__ TsQ,
        const float* __restrict__ TcK, const float* __restrict__ TsK,
        float* __restrict__ FQ, float* __restrict__ FK) {
    int bid = blockIdx.x;
    int xcd = bid & 7, j = bid >> 3;         // j in [0,320)
    int z = xcd + 8 * (j / 80);              // split*8 + inp*4 + b
    int rest = j % 80;
    int n0 = (rest % 5) * 64, m0 = (rest / 5) * 64;
    int split = z >> 3, zb = z & 7, inp = zb >> 2, b = zb & 3;
    const float* Tc = (inp ? TcK : TcQ) + (size_t)b * 524288;
    const float* Ts = (inp ? TsK : TsQ) + (size_t)b * 524288;
    float* F = (inp ? FK : FQ) + (size_t)b * 524288;
    __shared__ float Ac[16][68], Asn[16][68];     // [kk][m]
    __shared__ float Bc[16][68], Bs[16][68];      // [kk][n]
    int tn = threadIdx.x & 15, tm = threadIdx.x >> 4;
    int mA = threadIdx.x >> 2, kqA = threadIdx.x & 3;
    int colB = threadIdx.x & 63, rowB = threadIdx.x >> 6;
    float acc[4][4] = {};
    int kbeg = split * 256;
    int m = m0 + mA;
    for (int k0 = kbeg; k0 < kbeg + 256; k0 += 16) {
#pragma unroll
        for (int x = 0; x < 4; x++) {
            int k = k0 + 4 * kqA + x;
            int t = (m * k) & 1023;
            float ang = (float)t * TWO_PI_OVER_1024;
            Ac [4 * kqA + x][mA] = __cosf(ang);
            Asn[4 * kqA + x][mA] = __sinf(ang);
        }
#pragma unroll
        for (int r = 0; r < 4; r++) {
            Bc[rowB + 4 * r][colB] = Tc[(size_t)(k0 + rowB + 4 * r) * 512 + n0 + colB];
            Bs[rowB + 4 * r][colB] = Ts[(size_t)(k0 + rowB + 4 * r) * 512 + n0 + colB];
        }
        __syncthreads();
#pragma unroll
        for (int kk = 0; kk < 16; kk++) {
            float4 ac = *(const float4*)&Ac[kk][tm * 4];
            float4 as = *(const float4*)&Asn[kk][tm * 4];
            float4 bc = *(const float4*)&Bc[kk][tn * 4];
            float4 bs = *(const float4*)&Bs[kk][tn * 4];
            float acv[4] = {ac.x, ac.y, ac.z, ac.w};
            float asv[4] = {as.x, as.y, as.z, as.w};
            float bcv[4] = {bc.x, bc.y, bc.z, bc.w};
            float bsv[4] = {bs.x, bs.y, bs.z, bs.w};
#pragma unroll
            for (int i = 0; i < 4; i++)
#pragma unroll
                for (int jj = 0; jj < 4; jj++)
                    acc[i][jj] += acv[i] * bcv[jj] - asv[i] * bsv[jj];
        }
        __syncthreads();
    }
#pragma unroll
    for (int i = 0; i < 4; i++) {
        size_t rbase = (size_t)(m0 + tm * 4 + i) * 512 + n0 + tn * 4;
#pragma unroll
        for (int jj = 0; jj < 4; jj++)
            atomicAdd(&F[rbase + jj], acc[i][jj]);
    }
}

// ------------- mirror: F[m, n] = F[(1024-m)%1024, 512-n]  for n in 257..511
__global__ void mirror_f(float* __restrict__ FQ, float* __restrict__ FK) {
    int z = blockIdx.x >> 10;
    int m = blockIdx.x & 1023;
    float* F = (z >= 4) ? (FK + (size_t)(z - 4) * 524288) : (FQ + (size_t)z * 524288);
    int t = threadIdx.x;
    if (t < 255) {
        int n = 257 + t;
        F[(size_t)m * 512 + n] = F[(size_t)((1024 - m) & 1023) * 512 + (512 - n)];
    }
}

// ------------------------------------ multi-scale conv gather (all 4 scales)
template <int C>
__device__ inline float conv_gather(const float* __restrict__ Fb, int rb, int cb, int d,
                                    const float* __restrict__ w) {
    float acc = 0.f;
#pragma unroll
    for (int ci = 0; ci < C; ci++) {
        int u = ci * 64 + d;
        int q = u / C, r = u - q * C;
        int row = rb + r - C;
        int col = cb + q - C;
        if (row >= 0 && col >= 0)
            acc += w[ci] * Fb[(row << 9) + col];
    }
    return acc;
}

__global__ __launch_bounds__(256) void conv_all(const float* __restrict__ F,
        float* __restrict__ out,
        const float* __restrict__ w1, const float* __restrict__ bb1,
        const float* __restrict__ w3, const float* __restrict__ bb3,
        const float* __restrict__ w6, const float* __restrict__ bb6,
        const float* __restrict__ w9, const float* __restrict__ bb9,
        float scale) {
    int idx = blockIdx.x * 256 + threadIdx.x;
    int d = idx & 63;
    int l = (idx >> 6) & 1023;
    int h = (idx >> 16) & 7;
    int b = idx >> 19;
    int g = (h << 10) + l;
    int rb = g >> 3;
    int cb = (g & 7) << 6;
    const float* Fb = F + (size_t)b * (1024 * 512);
    size_t ob = (size_t)((b * 8 + h) * 4) * 65536 + l * 64 + d;
    out[ob]             = (conv_gather<1>(Fb, rb, cb, d, w1) + bb1[0]) * scale;
    out[ob + 65536]     = (conv_gather<3>(Fb, rb, cb, d, w3) + bb3[0]) * scale;
    out[ob + 2 * 65536] = (conv_gather<6>(Fb, rb, cb, d, w6) + bb6[0]) * scale;
    out[ob + 3 * 65536] = (conv_gather<9>(Fb, rb, cb, d, w9) + bb9[0]) * scale;
}

// ------------- fused scores (4 GEMMs K=64) + softmax over p + q-reduction
// __launch_bounds__(256,4): 128-VGPR budget -> acc stays in registers (no spill)
__global__ __launch_bounds__(256, 4) void scores_attn(const float* __restrict__ Qp,
                                                      const float* __restrict__ Kp,
                                                      float* __restrict__ attn_out) {
    int bid = blockIdx.x;
    int xcd = bid & 7, j = bid >> 3;        // j in [0,1024)
    int bh  = xcd + 8 * (j >> 8);           // [0,32)
    int qk  = j & 255;
    int q0  = (qk >> 4) << 6;
    int k0  = (qk & 15) << 6;
    __shared__ float Aq[64][68];   // [kk][q]
    __shared__ float Bk[64][68];   // [kk][k]
    int tn = threadIdx.x & 15, tm = threadIdx.x >> 4;
    float acc[4][4][4];   // [p][i(q)][j(k)]
#pragma unroll
    for (int p = 0; p < 4; p++)
#pragma unroll
        for (int i = 0; i < 4; i++)
#pragma unroll
            for (int j2 = 0; j2 < 4; j2++) acc[p][i][j2] = 0.f;

    for (int p = 0; p < 4; p++) {
        const float* Ab = Qp + (size_t)(bh * 4 + p) * 65536 + (size_t)q0 * 64;
        const float* Bb = Kp + (size_t)(bh * 4 + p) * 65536 + (size_t)k0 * 64;
        __syncthreads();
#pragma unroll
        for (int r = 0; r < 4; r++) {
            int rl = tm + 16 * r;               // local q (for A) / k (for B)
            float4 va = *(const float4*)&Ab[(size_t)rl * 64 + 4 * tn];
            float4 vb = *(const float4*)&Bb[(size_t)rl * 64 + 4 * tn];
            float av[4] = {va.x, va.y, va.z, va.w};
            float bv[4] = {vb.x, vb.y, vb.z, vb.w};
#pragma unroll
            for (int x = 0; x < 4; x++) {
                int kk = 4 * tn + x;
                int sw = ((kk >> 3) & 3) << 2;
                Aq[kk][rl ^ sw] = av[x];
                Bk[kk][rl ^ sw] = bv[x];
            }
        }
        __syncthreads();
#pragma unroll
        for (int kk = 0; kk < 64; kk++) {
            int sw = ((kk >> 3) & 3) << 2;
            float4 a = *(const float4*)&Aq[kk][(tm * 4) ^ sw];
            float4 b = *(const float4*)&Bk[kk][(tn * 4) ^ sw];
            float av[4] = {a.x, a.y, a.z, a.w};
            float bv[4] = {b.x, b.y, b.z, b.w};
#pragma unroll
            for (int i = 0; i < 4; i++)
#pragma unroll
                for (int j2 = 0; j2 < 4; j2++) acc[p][i][j2] += av[i] * bv[j2];
        }
    }

    // softmax over p per (q,k); accumulate over this thread's 4 q's
    float qsum[4][4];     // [p][j]
#pragma unroll
    for (int p = 0; p < 4; p++)
#pragma unroll
        for (int j2 = 0; j2 < 4; j2++) qsum[p][j2] = 0.f;
#pragma unroll
    for (int i = 0; i < 4; i++)
#pragma unroll
        for (int j2 = 0; j2 < 4; j2++) {
            float s0 = acc[0][i][j2], s1 = acc[1][i][j2];
            float s2 = acc[2][i][j2], s3 = acc[3][i][j2];
            float m = fmaxf(fmaxf(s0, s1), fmaxf(s2, s3));
            float e0 = __expf(s0 - m), e1 = __expf(s1 - m);
            float e2 = __expf(s2 - m), e3 = __expf(s3 - m);
            float inv = __builtin_amdgcn_rcpf(e0 + e1 + e2 + e3);
            qsum[0][j2] += e0 * inv; qsum[1][j2] += e1 * inv;
            qsum[2][j2] += e2 * inv; qsum[3][j2] += e3 * inv;
        }

    __syncthreads();       // inner-loop LDS reads done before red overwrite
    // red[t][pcol] with stride 257 (==1 mod 32): stores 2-way, loads clean
    float* red = &Aq[0][0];   // max idx 15*257+255 = 4110 < 4352
#pragma unroll
    for (int p = 0; p < 4; p++)
#pragma unroll
        for (int j2 = 0; j2 < 4; j2++)
            red[tm * 257 + p * 64 + tn * 4 + j2] = qsum[p][j2];
    __syncthreads();
    int pp = threadIdx.x >> 6, kk = threadIdx.x & 63;
    float s = 0.f;
#pragma unroll
    for (int t = 0; t < 16; t++) s += red[t * 257 + pp * 64 + kk];
    atomicAdd(&attn_out[(size_t)(bh * 4 + pp) * 1024 + k0 + kk], s);
}

// ------------------------------- context[b,h,q,:] = colsum(V[b,h]) broadcast
__global__ __launch_bounds__(256) void context_kernel(const float* __restrict__ V,
                                                      float* __restrict__ out) {
    int bh = blockIdx.x;
    const float* Vb = V + (size_t)bh * 65536;
    __shared__ float part[4][64];
    __shared__ float colsum[64];
    int d = threadIdx.x & 63, grp = threadIdx.x >> 6;
    float s = 0.f;
    for (int r = grp; r < 1024; r += 4) s += Vb[r * 64 + d];
    part[grp][d] = s;
    __syncthreads();
    if (threadIdx.x < 64) colsum[d] = part[0][d] + part[1][d] + part[2][d] + part[3][d];
    __syncthreads();
    float val = colsum[d];
    float* ob = out + (size_t)bh * 65536;
    for (int q = grp; q < 1024; q += 4) ob[q * 64 + d] = val;
}

// ---------------------------------------------------------------------------
extern "C" void kernel_launch(void* const* d_in, const int* in_sizes, int n_in,
                              void* d_out, int out_size, void* d_ws, size_t ws_size,
                              hipStream_t stream) {
    if (n_in < 19) return;
    if ((size_t)ws_size < WS_FLOATS_NEEDED * sizeof(float)) return;
    const float* Q = (const float*)d_in[0];
    const float* K = (const float*)d_in[1];
    const float* V = (const float*)d_in[2];
    const float* wq[4] = {(const float*)d_in[3], (const float*)d_in[5],
                          (const float*)d_in[7], (const float*)d_in[9]};
    const float* bq[4] = {(const float*)d_in[4], (const float*)d_in[6],
                          (const float*)d_in[8], (const float*)d_in[10]};
    const float* wk[4] = {(const float*)d_in[11], (const float*)d_in[13],
                          (const float*)d_in[15], (const float*)d_in[17]};
    const float* bk[4] = {(const float*)d_in[12], (const float*)d_in[14],
                          (const float*)d_in[16], (const float*)d_in[18]};

    float* ws  = (float*)d_ws;
    float* FQ  = ws;
    float* FK  = ws + 2097152;
    float* TcQ = ws + 6815744;
    float* TsQ = TcQ + 2097152;
    float* TcK = TsQ + 2097152;
    float* TsK = TcK + 2097152;
    float* Qp  = ws + 6815744;          // overlays T region (dead after stage2)
    float* Kp  = Qp + 8388608;

    float* ctx      = (float*)d_out;
    float* attn_out = ctx + 2097152;

    // zero atomic destinations
    hipMemsetAsync(attn_out, 0, 131072 * sizeof(float), stream);
    hipMemsetAsync(TcQ, 0, 8388608 * sizeof(float), stream);   // all 4 T arrays
    hipMemsetAsync(FQ, 0, 4194304 * sizeof(float), stream);    // FQ + FK

    // stage 1: K-split x2, XCD-grouped 1D grid, trig generated in-register
    stage1_fused<<<1280, 256, 0, stream>>>(Q, K, TcQ, TsQ, TcK, TsK);

    // stage 2: K-split x4, XCD-grouped 1D grid, trig generated in-register
    stage2_fused<<<2560, 256, 0, stream>>>(TcQ, TsQ, TcK, TsK, FQ, FK);

    // fill F columns 257..511 by conjugate symmetry
    mirror_f<<<8192, 256, 0, stream>>>(FQ, FK);

    // multi-scale conv gathers; SCALE folded into Qp
    conv_all<<<8192, 256, 0, stream>>>(FQ, Qp, wq[0], bq[0], wq[1], bq[1],
                                       wq[2], bq[2], wq[3], bq[3], SCALE);
    conv_all<<<8192, 256, 0, stream>>>(FK, Kp, wk[0], bk[0], wk[1], bk[1],
                                       wk[2], bk[2], wk[3], bk[3], 1.0f);

    // fused scores + softmax(p) + sum_q  -> attn_out (XCD-grouped 1D grid)
    scores_attn<<<8192, 256, 0, stream>>>(Qp, Kp, attn_out);

    // context = colsum(V) broadcast over q
    context_kernel<<<32, 256, 0, stream>>>(V, ctx);
}

// Round 7
// 1042.286 us; speedup vs baseline: 1.1224x; 1.1224x over previous
//
#include <hip/hip_runtime.h>

// Problem constants: Q,K,V (4,8,1024,64) f32.
#define SCALE 0.125f

// ws layout (float offsets) — no trig tables, no atomics anywhere
//  Fa:   0         (8 maps x 524288 = 4194304)   stage2 partial (k-half 0)
//  Fb:   4194304   (4194304)                     stage2 partial (k-half 1)
//  F:    8388608   (4194304)  FQ=F, FK=F+2097152 (combined+mirrored)
//  T:    12582912  (4 x 2097152 = 8388608)       TcQ,TsQ,TcK,TsK
//  Qp:   0         (8388608)  overlays Fa/Fb (dead after combine)
//  Kp:   12582912  (8388608)  overlays T (dead after stage2)
//  part: 20971520  (2097152)  scores partial sums
//  end:  23068672 floats
#define WS_FLOATS_NEEDED 23592960ull

#define TWO_PI_OVER_512  0.012271846303085129f
#define TWO_PI_OVER_1024 0.0061359231517425646f

// ---------------- stage1: Tc = X*CN, Ts = X*SN, cols 0..319, K=512 full
// tile 32(m) x 64(n), 1280 blocks, direct stores, trig in-register
__global__ __launch_bounds__(256) void stage1_fused(
        const float* __restrict__ Qg, const float* __restrict__ Kg,
        float* __restrict__ TcQ, float* __restrict__ TsQ,
        float* __restrict__ TcK, float* __restrict__ TsK) {
    int bid = blockIdx.x;
    int inp = bid / 640;
    int w = bid % 640;
    int m0 = (w / 5) * 32, n0 = (w % 5) * 64;
    const float* X = inp ? Kg : Qg;
    float* Tc = inp ? TcK : TcQ;
    float* Ts = inp ? TsK : TsQ;
    __shared__ float At[16][36];                  // [kk][m]
    __shared__ float Bc[16][68], Bs[16][68];      // [kk][n]
    int t = threadIdx.x;
    int tn = t & 15, tm = t >> 4;
    int mr = t >> 3, kq = t & 7;                  // A staging
    int colB = t & 63, rowB = t >> 6;             // B staging
    float accC[2][4] = {}, accS[2][4] = {};
    for (int k0 = 0; k0 < 512; k0 += 16) {
        float2 va = *(const float2*)&X[(size_t)(m0 + mr) * 512 + k0 + 2 * kq];
        At[2 * kq + 0][mr] = va.x;
        At[2 * kq + 1][mr] = va.y;
#pragma unroll
        for (int r = 0; r < 4; r++) {
            int k = k0 + rowB + 4 * r;
            int n = n0 + colB;
            int tt = (k * n) & 511;
            float ang = (float)tt * TWO_PI_OVER_512;
            Bc[rowB + 4 * r][colB] = __cosf(ang);
            Bs[rowB + 4 * r][colB] = __sinf(ang);
        }
        __syncthreads();
#pragma unroll
        for (int kk = 0; kk < 16; kk++) {
            float2 a  = *(const float2*)&At[kk][2 * tm];
            float4 bc = *(const float4*)&Bc[kk][4 * tn];
            float4 bs = *(const float4*)&Bs[kk][4 * tn];
            float av[2]  = {a.x, a.y};
            float bcv[4] = {bc.x, bc.y, bc.z, bc.w};
            float bsv[4] = {bs.x, bs.y, bs.z, bs.w};
#pragma unroll
            for (int i = 0; i < 2; i++)
#pragma unroll
                for (int j = 0; j < 4; j++) {
                    accC[i][j] += av[i] * bcv[j];
                    accS[i][j] += av[i] * bsv[j];
                }
        }
        __syncthreads();
    }
#pragma unroll
    for (int i = 0; i < 2; i++) {
        size_t rbase = (size_t)(m0 + 2 * tm + i) * 512 + n0 + 4 * tn;
        *(float4*)&Tc[rbase] = make_float4(accC[i][0], accC[i][1], accC[i][2], accC[i][3]);
        *(float4*)&Ts[rbase] = make_float4(accS[i][0], accS[i][1], accS[i][2], accS[i][3]);
    }
}

// ---------------- stage2: Fpart[s] = CM*Tc - SM*Ts over k-half s, cols 0..319
// 1280 blocks: map=bid&7 (XCD owns its 4MB T-panel), split in {0,1}, direct stores
__global__ __launch_bounds__(256) void stage2_fused(
        const float* __restrict__ TcQ, const float* __restrict__ TsQ,
        const float* __restrict__ TcK, const float* __restrict__ TsK,
        float* __restrict__ Fa, float* __restrict__ Fb) {
    int bid = blockIdx.x;
    int map = bid & 7;                       // inp*4 + b
    int r = bid >> 3;                        // [0,160)
    int split = r / 80, rest = r % 80;
    int n0 = (rest % 5) * 64, m0 = (rest / 5) * 64;
    int inp = map >> 2, b = map & 3;
    const float* Tc = (inp ? TcK : TcQ) + (size_t)b * 524288;
    const float* Ts = (inp ? TsK : TsQ) + (size_t)b * 524288;
    float* Fp = (split ? Fb : Fa) + (size_t)map * 524288;
    __shared__ float Ac[16][68], Asn[16][68];     // [kk][m]
    __shared__ float Bc[16][68], Bs[16][68];      // [kk][n]
    int t = threadIdx.x;
    int tn = t & 15, tm = t >> 4;
    int mA = t >> 2, kqA = t & 3;
    int colB = t & 63, rowB = t >> 6;
    float acc[4][4] = {};
    int kbeg = split * 512;
    int m = m0 + mA;
    for (int k0 = kbeg; k0 < kbeg + 512; k0 += 16) {
#pragma unroll
        for (int x = 0; x < 4; x++) {
            int k = k0 + 4 * kqA + x;
            int tt = (m * k) & 1023;
            float ang = (float)tt * TWO_PI_OVER_1024;
            Ac [4 * kqA + x][mA] = __cosf(ang);
            Asn[4 * kqA + x][mA] = __sinf(ang);
        }
#pragma unroll
        for (int rr = 0; rr < 4; rr++) {
            Bc[rowB + 4 * rr][colB] = Tc[(size_t)(k0 + rowB + 4 * rr) * 512 + n0 + colB];
            Bs[rowB + 4 * rr][colB] = Ts[(size_t)(k0 + rowB + 4 * rr) * 512 + n0 + colB];
        }
        __syncthreads();
#pragma unroll
        for (int kk = 0; kk < 16; kk++) {
            float4 ac = *(const float4*)&Ac[kk][4 * tm];
            float4 as = *(const float4*)&Asn[kk][4 * tm];
            float4 bc = *(const float4*)&Bc[kk][4 * tn];
            float4 bs = *(const float4*)&Bs[kk][4 * tn];
            float acv[4] = {ac.x, ac.y, ac.z, ac.w};
            float asv[4] = {as.x, as.y, as.z, as.w};
            float bcv[4] = {bc.x, bc.y, bc.z, bc.w};
            float bsv[4] = {bs.x, bs.y, bs.z, bs.w};
#pragma unroll
            for (int i = 0; i < 4; i++)
#pragma unroll
                for (int jj = 0; jj < 4; jj++)
                    acc[i][jj] += acv[i] * bcv[jj] - asv[i] * bsv[jj];
        }
        __syncthreads();
    }
#pragma unroll
    for (int i = 0; i < 4; i++) {
        size_t rbase = (size_t)(m0 + 4 * tm + i) * 512 + n0 + 4 * tn;
        *(float4*)&Fp[rbase] = make_float4(acc[i][0], acc[i][1], acc[i][2], acc[i][3]);
    }
}

// ------- combine partials + Hermitian mirror:  F[m][n] for all n in [0,512)
// n<=256: Fa+Fb at (m,n);  n>=257: Fa+Fb at ((1024-m)%1024, 512-n)
__global__ __launch_bounds__(256) void combine_mirror(
        const float* __restrict__ Fa, const float* __restrict__ Fb,
        float* __restrict__ F) {
    int map = blockIdx.x >> 10;
    int m = blockIdx.x & 1023;
    int t = threadIdx.x;
    const float* fa = Fa + (size_t)map * 524288;
    const float* fb = Fb + (size_t)map * 524288;
    float* fo = F + (size_t)map * 524288;
    size_t rowd = (size_t)m * 512;
    // direct cols 0..255
    fo[rowd + t] = fa[rowd + t] + fb[rowd + t];
    if (t == 0)  // col 256
        fo[rowd + 256] = fa[rowd + 256] + fb[rowd + 256];
    // mirror cols 257..511 from source col 255-t of row (1024-m)%1024
    if (t < 255) {
        size_t rows = (size_t)((1024 - m) & 1023) * 512;
        fo[rowd + 257 + t] = fa[rows + 255 - t] + fb[rows + 255 - t];
    }
}

// ------------------------------------ multi-scale conv gather (all 4 scales)
template <int C>
__device__ inline float conv_gather(const float* __restrict__ Fb, int rb, int cb, int d,
                                    const float* __restrict__ w) {
    float acc = 0.f;
#pragma unroll
    for (int ci = 0; ci < C; ci++) {
        int u = ci * 64 + d;
        int q = u / C, r = u - q * C;
        int row = rb + r - C;
        int col = cb + q - C;
        if (row >= 0 && col >= 0)
            acc += w[ci] * Fb[(row << 9) + col];
    }
    return acc;
}

__global__ __launch_bounds__(256) void conv_all(const float* __restrict__ F,
        float* __restrict__ out,
        const float* __restrict__ w1, const float* __restrict__ bb1,
        const float* __restrict__ w3, const float* __restrict__ bb3,
        const float* __restrict__ w6, const float* __restrict__ bb6,
        const float* __restrict__ w9, const float* __restrict__ bb9,
        float scale) {
    int idx = blockIdx.x * 256 + threadIdx.x;
    int d = idx & 63;
    int l = (idx >> 6) & 1023;
    int h = (idx >> 16) & 7;
    int b = idx >> 19;
    int g = (h << 10) + l;
    int rb = g >> 3;
    int cb = (g & 7) << 6;
    const float* Fb = F + (size_t)b * (1024 * 512);
    size_t ob = (size_t)((b * 8 + h) * 4) * 65536 + l * 64 + d;
    out[ob]             = (conv_gather<1>(Fb, rb, cb, d, w1) + bb1[0]) * scale;
    out[ob + 65536]     = (conv_gather<3>(Fb, rb, cb, d, w3) + bb3[0]) * scale;
    out[ob + 2 * 65536] = (conv_gather<6>(Fb, rb, cb, d, w6) + bb6[0]) * scale;
    out[ob + 3 * 65536] = (conv_gather<9>(Fb, rb, cb, d, w9) + bb9[0]) * scale;
}

// ------------- fused scores (4 GEMMs K=64) + softmax over p + q-partials
// 1D grid 8192; XCD x owns bh = x, x+8, x+16, x+24; NO atomics (partials out)
__global__ __launch_bounds__(256, 4) void scores_attn(const float* __restrict__ Qp,
                                                      const float* __restrict__ Kp,
                                                      float* __restrict__ part) {
    int bid = blockIdx.x;
    int xcd = bid & 7, j = bid >> 3;        // j in [0,1024)
    int bh  = xcd + 8 * (j >> 8);           // [0,32)
    int qk  = j & 255;
    int qt  = qk >> 4;
    int q0  = qt << 6;
    int k0  = (qk & 15) << 6;
    __shared__ float Aq[64][68];   // [kk][q]
    __shared__ float Bk[64][68];   // [kk][k]
    int tn = threadIdx.x & 15, tm = threadIdx.x >> 4;
    float acc[4][4][4];   // [p][i(q)][j(k)]
#pragma unroll
    for (int p = 0; p < 4; p++)
#pragma unroll
        for (int i = 0; i < 4; i++)
#pragma unroll
            for (int j2 = 0; j2 < 4; j2++) acc[p][i][j2] = 0.f;

    for (int p = 0; p < 4; p++) {
        const float* Ab = Qp + (size_t)(bh * 4 + p) * 65536 + (size_t)q0 * 64;
        const float* Bb = Kp + (size_t)(bh * 4 + p) * 65536 + (size_t)k0 * 64;
        __syncthreads();
#pragma unroll
        for (int r = 0; r < 4; r++) {
            int rl = tm + 16 * r;               // local q (for A) / k (for B)
            float4 va = *(const float4*)&Ab[(size_t)rl * 64 + 4 * tn];
            float4 vb = *(const float4*)&Bb[(size_t)rl * 64 + 4 * tn];
            float av[4] = {va.x, va.y, va.z, va.w};
            float bv[4] = {vb.x, vb.y, vb.z, vb.w};
#pragma unroll
            for (int x = 0; x < 4; x++) {
                int kk = 4 * tn + x;
                int sw = ((kk >> 3) & 3) << 2;
                Aq[kk][rl ^ sw] = av[x];
                Bk[kk][rl ^ sw] = bv[x];
            }
        }
        __syncthreads();
#pragma unroll
        for (int kk = 0; kk < 64; kk++) {
            int sw = ((kk >> 3) & 3) << 2;
            float4 a = *(const float4*)&Aq[kk][(tm * 4) ^ sw];
            float4 b = *(const float4*)&Bk[kk][(tn * 4) ^ sw];
            float av[4] = {a.x, a.y, a.z, a.w};
            float bv[4] = {b.x, b.y, b.z, b.w};
#pragma unroll
            for (int i = 0; i < 4; i++)
#pragma unroll
                for (int j2 = 0; j2 < 4; j2++) acc[p][i][j2] += av[i] * bv[j2];
        }
    }

    // softmax over p per (q,k); accumulate over this thread's 4 q's
    float qsum[4][4];     // [p][j]
#pragma unroll
    for (int p = 0; p < 4; p++)
#pragma unroll
        for (int j2 = 0; j2 < 4; j2++) qsum[p][j2] = 0.f;
#pragma unroll
    for (int i = 0; i < 4; i++)
#pragma unroll
        for (int j2 = 0; j2 < 4; j2++) {
            float s0 = acc[0][i][j2], s1 = acc[1][i][j2];
            float s2 = acc[2][i][j2], s3 = acc[3][i][j2];
            float m = fmaxf(fmaxf(s0, s1), fmaxf(s2, s3));
            float e0 = __expf(s0 - m), e1 = __expf(s1 - m);
            float e2 = __expf(s2 - m), e3 = __expf(s3 - m);
            float inv = __builtin_amdgcn_rcpf(e0 + e1 + e2 + e3);
            qsum[0][j2] += e0 * inv; qsum[1][j2] += e1 * inv;
            qsum[2][j2] += e2 * inv; qsum[3][j2] += e3 * inv;
        }

    __syncthreads();       // inner-loop LDS reads done before red overwrite
    // red[t][pcol] with stride 257 (==1 mod 32): stores 2-way, loads clean
    float* red = &Aq[0][0];   // max idx 15*257+255 = 4110 < 4352
#pragma unroll
    for (int p = 0; p < 4; p++)
#pragma unroll
        for (int j2 = 0; j2 < 4; j2++)
            red[tm * 257 + p * 64 + tn * 4 + j2] = qsum[p][j2];
    __syncthreads();
    int pp = threadIdx.x >> 6, kk2 = threadIdx.x & 63;
    float s = 0.f;
#pragma unroll
    for (int tt = 0; tt < 16; tt++) s += red[tt * 257 + pp * 64 + kk2];
    part[((size_t)(bh * 4 + pp) * 16 + qt) * 1024 + k0 + kk2] = s;
}

// ------------- attn_out[bhp][k] = sum over 16 q-tiles of part[bhp][qt][k]
__global__ __launch_bounds__(256) void attn_reduce(const float* __restrict__ part,
                                                   float* __restrict__ attn_out) {
    int idx = blockIdx.x * 256 + threadIdx.x;   // [0, 131072)
    int bhp = idx >> 10, k = idx & 1023;
    const float* pb = part + (size_t)bhp * 16384 + k;
    float s = 0.f;
#pragma unroll
    for (int qt = 0; qt < 16; qt++) s += pb[qt * 1024];
    attn_out[idx] = s;
}

// ------------------------------- context[b,h,q,:] = colsum(V[b,h]) broadcast
__global__ __launch_bounds__(256) void context_kernel(const float* __restrict__ V,
                                                      float* __restrict__ out) {
    int bh = blockIdx.x;
    const float* Vb = V + (size_t)bh * 65536;
    __shared__ float part[4][64];
    __shared__ float colsum[64];
    int d = threadIdx.x & 63, grp = threadIdx.x >> 6;
    float s = 0.f;
    for (int r = grp; r < 1024; r += 4) s += Vb[r * 64 + d];
    part[grp][d] = s;
    __syncthreads();
    if (threadIdx.x < 64) colsum[d] = part[0][d] + part[1][d] + part[2][d] + part[3][d];
    __syncthreads();
    float val = colsum[d];
    float* ob = out + (size_t)bh * 65536;
    for (int q = grp; q < 1024; q += 4) ob[q * 64 + d] = val;
}

// ---------------------------------------------------------------------------
extern "C" void kernel_launch(void* const* d_in, const int* in_sizes, int n_in,
                              void* d_out, int out_size, void* d_ws, size_t ws_size,
                              hipStream_t stream) {
    if (n_in < 19) return;
    if ((size_t)ws_size < WS_FLOATS_NEEDED * sizeof(float)) return;
    const float* Q = (const float*)d_in[0];
    const float* K = (const float*)d_in[1];
    const float* V = (const float*)d_in[2];
    const float* wq[4] = {(const float*)d_in[3], (const float*)d_in[5],
                          (const float*)d_in[7], (const float*)d_in[9]};
    const float* bq[4] = {(const float*)d_in[4], (const float*)d_in[6],
                          (const float*)d_in[8], (const float*)d_in[10]};
    const float* wk[4] = {(const float*)d_in[11], (const float*)d_in[13],
                          (const float*)d_in[15], (const float*)d_in[17]};
    const float* bk[4] = {(const float*)d_in[12], (const float*)d_in[14],
                          (const float*)d_in[16], (const float*)d_in[18]};

    float* ws   = (float*)d_ws;
    float* Fa   = ws;                    // 4194304
    float* Fb   = ws + 4194304;          // 4194304
    float* F    = ws + 8388608;          // 4194304 (FQ=F, FK=F+2097152)
    float* TcQ  = ws + 12582912;
    float* TsQ  = TcQ + 2097152;
    float* TcK  = TsQ + 2097152;
    float* TsK  = TcK + 2097152;
    float* Qp   = ws;                    // overlays Fa/Fb (dead after combine)
    float* Kp   = ws + 12582912;         // overlays T (dead after stage2)
    float* part = ws + 20971520;         // 2097152

    float* ctx      = (float*)d_out;
    float* attn_out = ctx + 2097152;

    // stage 1: row-DFT GEMMs, direct stores
    stage1_fused<<<1280, 256, 0, stream>>>(Q, K, TcQ, TsQ, TcK, TsK);

    // stage 2: col-DFT GEMMs, K-split x2 into disjoint partials
    stage2_fused<<<1280, 256, 0, stream>>>(TcQ, TsQ, TcK, TsK, Fa, Fb);

    // combine partials + fill cols 257..511 by conjugate symmetry
    combine_mirror<<<8192, 256, 0, stream>>>(Fa, Fb, F);

    // multi-scale conv gathers; SCALE folded into Qp
    conv_all<<<8192, 256, 0, stream>>>(F, Qp, wq[0], bq[0], wq[1], bq[1],
                                       wq[2], bq[2], wq[3], bq[3], SCALE);
    conv_all<<<8192, 256, 0, stream>>>(F + 2097152, Kp, wk[0], bk[0], wk[1], bk[1],
                                       wk[2], bk[2], wk[3], bk[3], 1.0f);

    // fused scores + softmax(p) + per-tile q-sums -> part (no atomics)
    scores_attn<<<8192, 256, 0, stream>>>(Qp, Kp, part);

    // reduce q-tile partials -> attn_out
    attn_reduce<<<512, 256, 0, stream>>>(part, attn_out);

    // context = colsum(V) broadcast over q
    context_kernel<<<32, 256, 0, stream>>>(V, ctx);
}

// Round 10
// 897.813 us; speedup vs baseline: 1.3030x; 1.1609x over previous
//
#include <hip/hip_runtime.h>

// Problem constants: Q,K,V (4,8,1024,64) f32.
#define SCALE 0.125f

// ws layout (float offsets) — no trig tables, no atomics anywhere
//  Fa:   0         (8 maps x 524288 = 4194304)   stage2 partial (k-half 0)
//  Fb:   4194304   (4194304)                     stage2 partial (k-half 1)
//  F:    8388608   (4194304)  FQ=F, FK=F+2097152 (combined+mirrored)
//  T:    12582912  (4 x 2097152 = 8388608)       TcQ,TsQ,TcK,TsK
//  Qp:   0         (8388608)  overlays Fa/Fb (dead after combine)
//  Kp:   12582912  (8388608)  overlays T (dead after stage2)
//  part: 20971520  (2097152)  scores partial sums
//  end:  23068672 floats
#define WS_FLOATS_NEEDED 23592960ull

#define TWO_PI_OVER_512  0.012271846303085129f
#define TWO_PI_OVER_1024 0.0061359231517425646f

// ---------------- stage1: Tc = X*CN, Ts = X*SN, cols 0..319, K=512 full
// tile 32(m) x 64(n), 1280 blocks, direct stores, trig in-register
__global__ __launch_bounds__(256) void stage1_fused(
        const float* __restrict__ Qg, const float* __restrict__ Kg,
        float* __restrict__ TcQ, float* __restrict__ TsQ,
        float* __restrict__ TcK, float* __restrict__ TsK) {
    int bid = blockIdx.x;
    int inp = bid / 640;
    int w = bid % 640;
    int m0 = (w / 5) * 32, n0 = (w % 5) * 64;
    const float* X = inp ? Kg : Qg;
    float* Tc = inp ? TcK : TcQ;
    float* Ts = inp ? TsK : TsQ;
    __shared__ float At[16][36];                  // [kk][m]
    __shared__ float Bc[16][68], Bs[16][68];      // [kk][n]
    int t = threadIdx.x;
    int tn = t & 15, tm = t >> 4;
    int mr = t >> 3, kq = t & 7;                  // A staging
    int colB = t & 63, rowB = t >> 6;             // B staging
    float accC[2][4] = {}, accS[2][4] = {};
    for (int k0 = 0; k0 < 512; k0 += 16) {
        float2 va = *(const float2*)&X[(size_t)(m0 + mr) * 512 + k0 + 2 * kq];
        At[2 * kq + 0][mr] = va.x;
        At[2 * kq + 1][mr] = va.y;
#pragma unroll
        for (int r = 0; r < 4; r++) {
            int k = k0 + rowB + 4 * r;
            int n = n0 + colB;
            int tt = (k * n) & 511;
            float ang = (float)tt * TWO_PI_OVER_512;
            Bc[rowB + 4 * r][colB] = __cosf(ang);
            Bs[rowB + 4 * r][colB] = __sinf(ang);
        }
        __syncthreads();
#pragma unroll
        for (int kk = 0; kk < 16; kk++) {
            float2 a  = *(const float2*)&At[kk][2 * tm];
            float4 bc = *(const float4*)&Bc[kk][4 * tn];
            float4 bs = *(const float4*)&Bs[kk][4 * tn];
            float av[2]  = {a.x, a.y};
            float bcv[4] = {bc.x, bc.y, bc.z, bc.w};
            float bsv[4] = {bs.x, bs.y, bs.z, bs.w};
#pragma unroll
            for (int i = 0; i < 2; i++)
#pragma unroll
                for (int j = 0; j < 4; j++) {
                    accC[i][j] += av[i] * bcv[j];
                    accS[i][j] += av[i] * bsv[j];
                }
        }
        __syncthreads();
    }
#pragma unroll
    for (int i = 0; i < 2; i++) {
        size_t rbase = (size_t)(m0 + 2 * tm + i) * 512 + n0 + 4 * tn;
        *(float4*)&Tc[rbase] = make_float4(accC[i][0], accC[i][1], accC[i][2], accC[i][3]);
        *(float4*)&Ts[rbase] = make_float4(accS[i][0], accS[i][1], accS[i][2], accS[i][3]);
    }
}

// ---------------- stage2: Fpart[s] = CM*Tc - SM*Ts over k-half s, cols 0..319
// 1280 blocks: map=bid&7 (XCD owns its 4MB T-panel), split in {0,1}, direct stores
__global__ __launch_bounds__(256) void stage2_fused(
        const float* __restrict__ TcQ, const float* __restrict__ TsQ,
        const float* __restrict__ TcK, const float* __restrict__ TsK,
        float* __restrict__ Fa, float* __restrict__ Fb) {
    int bid = blockIdx.x;
    int map = bid & 7;                       // inp*4 + b
    int r = bid >> 3;                        // [0,160)
    int split = r / 80, rest = r % 80;
    int n0 = (rest % 5) * 64, m0 = (rest / 5) * 64;
    int inp = map >> 2, b = map & 3;
    const float* Tc = (inp ? TcK : TcQ) + (size_t)b * 524288;
    const float* Ts = (inp ? TsK : TsQ) + (size_t)b * 524288;
    float* Fp = (split ? Fb : Fa) + (size_t)map * 524288;
    __shared__ float Ac[16][68], Asn[16][68];     // [kk][m]
    __shared__ float Bc[16][68], Bs[16][68];      // [kk][n]
    int t = threadIdx.x;
    int tn = t & 15, tm = t >> 4;
    int mA = t >> 2, kqA = t & 3;
    int colB = t & 63, rowB = t >> 6;
    float acc[4][4] = {};
    int kbeg = split * 512;
    int m = m0 + mA;
    for (int k0 = kbeg; k0 < kbeg + 512; k0 += 16) {
#pragma unroll
        for (int x = 0; x < 4; x++) {
            int k = k0 + 4 * kqA + x;
            int tt = (m * k) & 1023;
            float ang = (float)tt * TWO_PI_OVER_1024;
            Ac [4 * kqA + x][mA] = __cosf(ang);
            Asn[4 * kqA + x][mA] = __sinf(ang);
        }
#pragma unroll
        for (int rr = 0; rr < 4; rr++) {
            Bc[rowB + 4 * rr][colB] = Tc[(size_t)(k0 + rowB + 4 * rr) * 512 + n0 + colB];
            Bs[rowB + 4 * rr][colB] = Ts[(size_t)(k0 + rowB + 4 * rr) * 512 + n0 + colB];
        }
        __syncthreads();
#pragma unroll
        for (int kk = 0; kk < 16; kk++) {
            float4 ac = *(const float4*)&Ac[kk][4 * tm];
            float4 as = *(const float4*)&Asn[kk][4 * tm];
            float4 bc = *(const float4*)&Bc[kk][4 * tn];
            float4 bs = *(const float4*)&Bs[kk][4 * tn];
            float acv[4] = {ac.x, ac.y, ac.z, ac.w};
            float asv[4] = {as.x, as.y, as.z, as.w};
            float bcv[4] = {bc.x, bc.y, bc.z, bc.w};
            float bsv[4] = {bs.x, bs.y, bs.z, bs.w};
#pragma unroll
            for (int i = 0; i < 4; i++)
#pragma unroll
                for (int jj = 0; jj < 4; jj++)
                    acc[i][jj] += acv[i] * bcv[jj] - asv[i] * bsv[jj];
        }
        __syncthreads();
    }
#pragma unroll
    for (int i = 0; i < 4; i++) {
        size_t rbase = (size_t)(m0 + 4 * tm + i) * 512 + n0 + 4 * tn;
        *(float4*)&Fp[rbase] = make_float4(acc[i][0], acc[i][1], acc[i][2], acc[i][3]);
    }
}

// ------- combine partials + Hermitian mirror:  F[m][n] for all n in [0,512)
__global__ __launch_bounds__(256) void combine_mirror(
        const float* __restrict__ Fa, const float* __restrict__ Fb,
        float* __restrict__ F) {
    int map = blockIdx.x >> 10;
    int m = blockIdx.x & 1023;
    int t = threadIdx.x;
    const float* fa = Fa + (size_t)map * 524288;
    const float* fb = Fb + (size_t)map * 524288;
    float* fo = F + (size_t)map * 524288;
    size_t rowd = (size_t)m * 512;
    fo[rowd + t] = fa[rowd + t] + fb[rowd + t];
    if (t == 0)
        fo[rowd + 256] = fa[rowd + 256] + fb[rowd + 256];
    if (t < 255) {
        size_t rows = (size_t)((1024 - m) & 1023) * 512;
        fo[rowd + 257 + t] = fa[rows + 255 - t] + fb[rows + 255 - t];
    }
}

// ------------------------------------ multi-scale conv gather (all 4 scales)
template <int C>
__device__ inline float conv_gather(const float* __restrict__ Fb, int rb, int cb, int d,
                                    const float* __restrict__ w) {
    float acc = 0.f;
#pragma unroll
    for (int ci = 0; ci < C; ci++) {
        int u = ci * 64 + d;
        int q = u / C, r = u - q * C;
        int row = rb + r - C;
        int col = cb + q - C;
        if (row >= 0 && col >= 0)
            acc += w[ci] * Fb[(row << 9) + col];
    }
    return acc;
}

__global__ __launch_bounds__(256) void conv_all(const float* __restrict__ F,
        float* __restrict__ out,
        const float* __restrict__ w1, const float* __restrict__ bb1,
        const float* __restrict__ w3, const float* __restrict__ bb3,
        const float* __restrict__ w6, const float* __restrict__ bb6,
        const float* __restrict__ w9, const float* __restrict__ bb9,
        float scale) {
    int idx = blockIdx.x * 256 + threadIdx.x;
    int d = idx & 63;
    int l = (idx >> 6) & 1023;
    int h = (idx >> 16) & 7;
    int b = idx >> 19;
    int g = (h << 10) + l;
    int rb = g >> 3;
    int cb = (g & 7) << 6;
    const float* Fb = F + (size_t)b * (1024 * 512);
    size_t ob = (size_t)((b * 8 + h) * 4) * 65536 + l * 64 + d;
    out[ob]             = (conv_gather<1>(Fb, rb, cb, d, w1) + bb1[0]) * scale;
    out[ob + 65536]     = (conv_gather<3>(Fb, rb, cb, d, w3) + bb3[0]) * scale;
    out[ob + 2 * 65536] = (conv_gather<6>(Fb, rb, cb, d, w6) + bb6[0]) * scale;
    out[ob + 3 * 65536] = (conv_gather<9>(Fb, rb, cb, d, w9) + bb9[0]) * scale;
}

// ------------- fused scores (4 GEMMs K=64) + softmax over p + q-partials
// p-loop UNROLLED so acc[p][i][j] is always statically indexed (rule #20:
// runtime-indexed arrays go to scratch -> was 1.08 GB WRITE_SIZE/dispatch)
__global__ __launch_bounds__(256, 4) void scores_attn(const float* __restrict__ Qp,
                                                      const float* __restrict__ Kp,
                                                      float* __restrict__ part) {
    int bid = blockIdx.x;
    int xcd = bid & 7, j = bid >> 3;        // j in [0,1024)
    int bh  = xcd + 8 * (j >> 8);           // [0,32)
    int qk  = j & 255;
    int qt  = qk >> 4;
    int q0  = qt << 6;
    int k0  = (qk & 15) << 6;
    __shared__ float Aq[64][68];   // [kk][q]
    __shared__ float Bk[64][68];   // [kk][k]
    int tn = threadIdx.x & 15, tm = threadIdx.x >> 4;
    float acc[4][4][4];   // [p][i(q)][j(k)] — all indices compile-time constant
#pragma unroll
    for (int p = 0; p < 4; p++)
#pragma unroll
        for (int i = 0; i < 4; i++)
#pragma unroll
            for (int j2 = 0; j2 < 4; j2++) acc[p][i][j2] = 0.f;

#pragma unroll
    for (int p = 0; p < 4; p++) {
        const float* Ab = Qp + (size_t)(bh * 4 + p) * 65536 + (size_t)q0 * 64;
        const float* Bb = Kp + (size_t)(bh * 4 + p) * 65536 + (size_t)k0 * 64;
        __syncthreads();
#pragma unroll
        for (int r = 0; r < 4; r++) {
            int rl = tm + 16 * r;               // local q (for A) / k (for B)
            float4 va = *(const float4*)&Ab[(size_t)rl * 64 + 4 * tn];
            float4 vb = *(const float4*)&Bb[(size_t)rl * 64 + 4 * tn];
            float av[4] = {va.x, va.y, va.z, va.w};
            float bv[4] = {vb.x, vb.y, vb.z, vb.w};
#pragma unroll
            for (int x = 0; x < 4; x++) {
                int kk = 4 * tn + x;
                int sw = ((kk >> 3) & 3) << 2;
                Aq[kk][rl ^ sw] = av[x];
                Bk[kk][rl ^ sw] = bv[x];
            }
        }
        __syncthreads();
#pragma unroll
        for (int kk = 0; kk < 64; kk++) {
            int sw = ((kk >> 3) & 3) << 2;
            float4 a = *(const float4*)&Aq[kk][(tm * 4) ^ sw];
            float4 b = *(const float4*)&Bk[kk][(tn * 4) ^ sw];
            float av[4] = {a.x, a.y, a.z, a.w};
            float bv[4] = {b.x, b.y, b.z, b.w};
#pragma unroll
            for (int i = 0; i < 4; i++)
#pragma unroll
                for (int j2 = 0; j2 < 4; j2++) acc[p][i][j2] += av[i] * bv[j2];
        }
    }

    // softmax over p per (q,k); accumulate over this thread's 4 q's
    float qsum[4][4];     // [p][j]
#pragma unroll
    for (int p = 0; p < 4; p++)
#pragma unroll
        for (int j2 = 0; j2 < 4; j2++) qsum[p][j2] = 0.f;
#pragma unroll
    for (int i = 0; i < 4; i++)
#pragma unroll
        for (int j2 = 0; j2 < 4; j2++) {
            float s0 = acc[0][i][j2], s1 = acc[1][i][j2];
            float s2 = acc[2][i][j2], s3 = acc[3][i][j2];
            float m = fmaxf(fmaxf(s0, s1), fmaxf(s2, s3));
            float e0 = __expf(s0 - m), e1 = __expf(s1 - m);
            float e2 = __expf(s2 - m), e3 = __expf(s3 - m);
            float inv = __builtin_amdgcn_rcpf(e0 + e1 + e2 + e3);
            qsum[0][j2] += e0 * inv; qsum[1][j2] += e1 * inv;
            qsum[2][j2] += e2 * inv; qsum[3][j2] += e3 * inv;
        }

    __syncthreads();       // inner-loop LDS reads done before red overwrite
    // red[t][pcol] with stride 257 (==1 mod 32): stores 2-way, loads clean
    float* red = &Aq[0][0];   // max idx 15*257+255 = 4110 < 4352
#pragma unroll
    for (int p = 0; p < 4; p++)
#pragma unroll
        for (int j2 = 0; j2 < 4; j2++)
            red[tm * 257 + p * 64 + tn * 4 + j2] = qsum[p][j2];
    __syncthreads();
    int pp = threadIdx.x >> 6, kk2 = threadIdx.x & 63;
    float s = 0.f;
#pragma unroll
    for (int tt = 0; tt < 16; tt++) s += red[tt * 257 + pp * 64 + kk2];
    part[((size_t)(bh * 4 + pp) * 16 + qt) * 1024 + k0 + kk2] = s;
}

// ------------- attn_out[bhp][k] = sum over 16 q-tiles of part[bhp][qt][k]
__global__ __launch_bounds__(256) void attn_reduce(const float* __restrict__ part,
                                                   float* __restrict__ attn_out) {
    int idx = blockIdx.x * 256 + threadIdx.x;   // [0, 131072)
    int bhp = idx >> 10, k = idx & 1023;
    const float* pb = part + (size_t)bhp * 16384 + k;
    float s = 0.f;
#pragma unroll
    for (int qt = 0; qt < 16; qt++) s += pb[qt * 1024];
    attn_out[idx] = s;
}

// ------------------------------- context[b,h,q,:] = colsum(V[b,h]) broadcast
__global__ __launch_bounds__(256) void context_kernel(const float* __restrict__ V,
                                                      float* __restrict__ out) {
    int bh = blockIdx.x;
    const float* Vb = V + (size_t)bh * 65536;
    __shared__ float part[4][64];
    __shared__ float colsum[64];
    int d = threadIdx.x & 63, grp = threadIdx.x >> 6;
    float s = 0.f;
    for (int r = grp; r < 1024; r += 4) s += Vb[r * 64 + d];
    part[grp][d] = s;
    __syncthreads();
    if (threadIdx.x < 64) colsum[d] = part[0][d] + part[1][d] + part[2][d] + part[3][d];
    __syncthreads();
    float val = colsum[d];
    float* ob = out + (size_t)bh * 65536;
    for (int q = grp; q < 1024; q += 4) ob[q * 64 + d] = val;
}

// ---------------------------------------------------------------------------
extern "C" void kernel_launch(void* const* d_in, const int* in_sizes, int n_in,
                              void* d_out, int out_size, void* d_ws, size_t ws_size,
                              hipStream_t stream) {
    if (n_in < 19) return;
    if ((size_t)ws_size < WS_FLOATS_NEEDED * sizeof(float)) return;
    const float* Q = (const float*)d_in[0];
    const float* K = (const float*)d_in[1];
    const float* V = (const float*)d_in[2];
    const float* wq[4] = {(const float*)d_in[3], (const float*)d_in[5],
                          (const float*)d_in[7], (const float*)d_in[9]};
    const float* bq[4] = {(const float*)d_in[4], (const float*)d_in[6],
                          (const float*)d_in[8], (const float*)d_in[10]};
    const float* wk[4] = {(const float*)d_in[11], (const float*)d_in[13],
                          (const float*)d_in[15], (const float*)d_in[17]};
    const float* bk[4] = {(const float*)d_in[12], (const float*)d_in[14],
                          (const float*)d_in[16], (const float*)d_in[18]};

    float* ws   = (float*)d_ws;
    float* Fa   = ws;                    // 4194304
    float* Fb   = ws + 4194304;          // 4194304
    float* F    = ws + 8388608;          // 4194304 (FQ=F, FK=F+2097152)
    float* TcQ  = ws + 12582912;
    float* TsQ  = TcQ + 2097152;
    float* TcK  = TsQ + 2097152;
    float* TsK  = TcK + 2097152;
    float* Qp   = ws;                    // overlays Fa/Fb (dead after combine)
    float* Kp   = ws + 12582912;         // overlays T (dead after stage2)
    float* part = ws + 20971520;         // 2097152

    float* ctx      = (float*)d_out;
    float* attn_out = ctx + 2097152;

    // stage 1: row-DFT GEMMs, direct stores
    stage1_fused<<<1280, 256, 0, stream>>>(Q, K, TcQ, TsQ, TcK, TsK);

    // stage 2: col-DFT GEMMs, K-split x2 into disjoint partials
    stage2_fused<<<1280, 256, 0, stream>>>(TcQ, TsQ, TcK, TsK, Fa, Fb);

    // combine partials + fill cols 257..511 by conjugate symmetry
    combine_mirror<<<8192, 256, 0, stream>>>(Fa, Fb, F);

    // multi-scale conv gathers; SCALE folded into Qp
    conv_all<<<8192, 256, 0, stream>>>(F, Qp, wq[0], bq[0], wq[1], bq[1],
                                       wq[2], bq[2], wq[3], bq[3], SCALE);
    conv_all<<<8192, 256, 0, stream>>>(F + 2097152, Kp, wk[0], bk[0], wk[1], bk[1],
                                       wk[2], bk[2], wk[3], bk[3], 1.0f);

    // fused scores + softmax(p) + per-tile q-sums -> part (no atomics)
    scores_attn<<<8192, 256, 0, stream>>>(Qp, Kp, part);

    // reduce q-tile partials -> attn_out
    attn_reduce<<<512, 256, 0, stream>>>(part, attn_out);

    // context = colsum(V) broadcast over q
    context_kernel<<<32, 256, 0, stream>>>(V, ctx);
}

// Round 11
// 803.554 us; speedup vs baseline: 1.4558x; 1.1173x over previous
//
#include <hip/hip_runtime.h>

// Problem constants: Q,K,V (4,8,1024,64) f32.
#define SCALE 0.125f

// ws layout (floats):
//  TcQ 0  TsQ 2097152  TcK 4194304  TsK 6291456          (stage1 out)
//  P   8388608  (4 splits x 8 maps x 1024 x 320 = 10485760)  stage2 partials
//  F   0        (8 maps x 524288 = 4194304)  overlays T (dead after stage2)
//  Qp  4194304  (8388608)  overlays TcK/TsK + P-head (dead after combine)
//  Kp  12582912 (8388608)  overlays P-tail
//  part 20971520 (2097152) scores partials
#define WS_FLOATS_NEEDED 23592960ull

#define TWO_PI_OVER_512  0.012271846303085129f
#define TWO_PI_OVER_1024 0.0061359231517425646f

// ---------------- stage1: Tc = X*CN, Ts = X*SN, cols 0..319, K=512 full
__global__ __launch_bounds__(256) void stage1_fused(
        const float* __restrict__ Qg, const float* __restrict__ Kg,
        float* __restrict__ TcQ, float* __restrict__ TsQ,
        float* __restrict__ TcK, float* __restrict__ TsK) {
    int bid = blockIdx.x;
    int inp = bid / 640;
    int w = bid % 640;
    int m0 = (w / 5) * 32, n0 = (w % 5) * 64;
    const float* X = inp ? Kg : Qg;
    float* Tc = inp ? TcK : TcQ;
    float* Ts = inp ? TsK : TsQ;
    __shared__ float At[16][36];                  // [kk][m]
    __shared__ float Bc[16][68], Bs[16][68];      // [kk][n]
    int t = threadIdx.x;
    int tn = t & 15, tm = t >> 4;
    int mr = t >> 3, kq = t & 7;                  // A staging
    int colB = t & 63, rowB = t >> 6;             // B staging
    float accC[2][4] = {}, accS[2][4] = {};
    for (int k0 = 0; k0 < 512; k0 += 16) {
        float2 va = *(const float2*)&X[(size_t)(m0 + mr) * 512 + k0 + 2 * kq];
        At[2 * kq + 0][mr] = va.x;
        At[2 * kq + 1][mr] = va.y;
#pragma unroll
        for (int r = 0; r < 4; r++) {
            int k = k0 + rowB + 4 * r;
            int n = n0 + colB;
            int tt = (k * n) & 511;
            float ang = (float)tt * TWO_PI_OVER_512;
            Bc[rowB + 4 * r][colB] = __cosf(ang);
            Bs[rowB + 4 * r][colB] = __sinf(ang);
        }
        __syncthreads();
#pragma unroll
        for (int kk = 0; kk < 16; kk++) {
            float2 a  = *(const float2*)&At[kk][2 * tm];
            float4 bc = *(const float4*)&Bc[kk][4 * tn];
            float4 bs = *(const float4*)&Bs[kk][4 * tn];
            float av[2]  = {a.x, a.y};
            float bcv[4] = {bc.x, bc.y, bc.z, bc.w};
            float bsv[4] = {bs.x, bs.y, bs.z, bs.w};
#pragma unroll
            for (int i = 0; i < 2; i++)
#pragma unroll
                for (int j = 0; j < 4; j++) {
                    accC[i][j] += av[i] * bcv[j];
                    accS[i][j] += av[i] * bsv[j];
                }
        }
        __syncthreads();
    }
#pragma unroll
    for (int i = 0; i < 2; i++) {
        size_t rbase = (size_t)(m0 + 2 * tm + i) * 512 + n0 + 4 * tn;
        *(float4*)&Tc[rbase] = make_float4(accC[i][0], accC[i][1], accC[i][2], accC[i][3]);
        *(float4*)&Ts[rbase] = make_float4(accS[i][0], accS[i][1], accS[i][2], accS[i][3]);
    }
}

// ---------------- stage2 v2: P[ks][map] = CM*Tc - SM*Ts over k-range, cols 0..319
// tile 256m x 64n, thread 8x8; A-side trig via in-register rotation (no LDS);
// B-panel (32 k-rows) reg-staged prefetch -> single LDS buffer.
// 640 blocks: map=bid&7 (XCD locality), (ks,mt,nt) in bid>>3.
__global__ __launch_bounds__(256) void stage2_fused(
        const float* __restrict__ TcQ, const float* __restrict__ TsQ,
        const float* __restrict__ TcK, const float* __restrict__ TsK,
        float* __restrict__ P) {
    int bid = blockIdx.x;
    int map = bid & 7;                       // inp*4 + b
    int rest = bid >> 3;                     // [0,80)
    int ks = rest / 20;
    int r2 = rest % 20;
    int mt = r2 / 5, nt = r2 % 5;
    int m0 = mt * 256, n0 = nt * 64;
    int inp = map >> 2, b = map & 3;
    const float* Tc = (inp ? TcK : TcQ) + (size_t)b * 524288;
    const float* Ts = (inp ? TsK : TsQ) + (size_t)b * 524288;
    float* Fp = P + (size_t)(ks * 8 + map) * 327680;   // 1024 x 320

    __shared__ float Bc[32][64], Bs[32][64];

    int t = threadIdx.x;
    int tm = t >> 3, tn = t & 7;      // tm 0..31 (m), tn 0..7 (n)
    int srow = t >> 3, scg = t & 7;   // staging: row 0..31, col-group 0..7

    int kbeg = ks * 256;
    // rotation state: c[i]+i*s[i] = exp(i * m_i * kbeg * th); step by m_i*th
    float c[8], s[8], cr[8], sr[8];
#pragma unroll
    for (int i = 0; i < 8; i++) {
        int m = m0 + tm * 8 + i;
        int t0 = (m * kbeg) & 1023;
        float a0 = (float)t0 * TWO_PI_OVER_1024;
        c[i] = __cosf(a0); s[i] = __sinf(a0);
        float a1 = (float)m * TWO_PI_OVER_1024;
        cr[i] = __cosf(a1); sr[i] = __sinf(a1);
    }
    float acc[8][8] = {};

    // prefetch panel 0 into regs
    float4 pc0, pc1, ps0, ps1;
    {
        const float* sc = &Tc[(size_t)(kbeg + srow) * 512 + n0 + scg * 8];
        pc0 = *(const float4*)sc; pc1 = *(const float4*)(sc + 4);
        const float* ss = &Ts[(size_t)(kbeg + srow) * 512 + n0 + scg * 8];
        ps0 = *(const float4*)ss; ps1 = *(const float4*)(ss + 4);
    }
    for (int kb = 0; kb < 8; kb++) {
        // write staged regs -> LDS
        *(float4*)&Bc[srow][scg * 8]     = pc0;
        *(float4*)&Bc[srow][scg * 8 + 4] = pc1;
        *(float4*)&Bs[srow][scg * 8]     = ps0;
        *(float4*)&Bs[srow][scg * 8 + 4] = ps1;
        __syncthreads();
        // issue next panel's loads (latency hides under the 32-k compute)
        if (kb < 7) {
            int kk0 = kbeg + (kb + 1) * 32;
            const float* sc = &Tc[(size_t)(kk0 + srow) * 512 + n0 + scg * 8];
            pc0 = *(const float4*)sc; pc1 = *(const float4*)(sc + 4);
            const float* ss = &Ts[(size_t)(kk0 + srow) * 512 + n0 + scg * 8];
            ps0 = *(const float4*)ss; ps1 = *(const float4*)(ss + 4);
        }
#pragma unroll 4
        for (int k = 0; k < 32; k++) {
            float4 b0 = *(const float4*)&Bc[k][tn * 8];
            float4 b1 = *(const float4*)&Bc[k][tn * 8 + 4];
            float4 v0 = *(const float4*)&Bs[k][tn * 8];
            float4 v1 = *(const float4*)&Bs[k][tn * 8 + 4];
            float bcv[8] = {b0.x, b0.y, b0.z, b0.w, b1.x, b1.y, b1.z, b1.w};
            float bsv[8] = {v0.x, v0.y, v0.z, v0.w, v1.x, v1.y, v1.z, v1.w};
#pragma unroll
            for (int i = 0; i < 8; i++) {
#pragma unroll
                for (int j = 0; j < 8; j++)
                    acc[i][j] += c[i] * bcv[j] - s[i] * bsv[j];
                float cn = c[i] * cr[i] - s[i] * sr[i];
                float sn = s[i] * cr[i] + c[i] * sr[i];
                c[i] = cn; s[i] = sn;
            }
        }
        __syncthreads();
    }
#pragma unroll
    for (int i = 0; i < 8; i++) {
        float* dst = &Fp[(size_t)(m0 + tm * 8 + i) * 320 + n0 + tn * 8];
        *(float4*)dst       = make_float4(acc[i][0], acc[i][1], acc[i][2], acc[i][3]);
        *(float4*)(dst + 4) = make_float4(acc[i][4], acc[i][5], acc[i][6], acc[i][7]);
    }
}

// ------- combine 4 partials + Hermitian mirror: F[m][n], n in [0,512)
__global__ __launch_bounds__(256) void combine_mirror(
        const float* __restrict__ P, float* __restrict__ F) {
    int map = blockIdx.x >> 10;
    int m = blockIdx.x & 1023;
    int t = threadIdx.x;
    const float* p0 = P + (size_t)(0 * 8 + map) * 327680;
    const float* p1 = P + (size_t)(1 * 8 + map) * 327680;
    const float* p2 = P + (size_t)(2 * 8 + map) * 327680;
    const float* p3 = P + (size_t)(3 * 8 + map) * 327680;
    float* fo = F + (size_t)map * 524288;
    size_t rs = (size_t)m * 320;
    fo[(size_t)m * 512 + t] = p0[rs + t] + p1[rs + t] + p2[rs + t] + p3[rs + t];
    if (t == 0)
        fo[(size_t)m * 512 + 256] = p0[rs + 256] + p1[rs + 256] + p2[rs + 256] + p3[rs + 256];
    if (t < 255) {
        size_t rm = (size_t)((1024 - m) & 1023) * 320 + 255 - t;
        fo[(size_t)m * 512 + 257 + t] = p0[rm] + p1[rm] + p2[rm] + p3[rm];
    }
}

// ------------------------------------ multi-scale conv gather (all 4 scales)
template <int C>
__device__ inline float conv_gather(const float* __restrict__ Fb, int rb, int cb, int d,
                                    const float* __restrict__ w) {
    float acc = 0.f;
#pragma unroll
    for (int ci = 0; ci < C; ci++) {
        int u = ci * 64 + d;
        int q = u / C, r = u - q * C;
        int row = rb + r - C;
        int col = cb + q - C;
        if (row >= 0 && col >= 0)
            acc += w[ci] * Fb[(row << 9) + col];
    }
    return acc;
}

__global__ __launch_bounds__(256) void conv_all(const float* __restrict__ F,
        float* __restrict__ out,
        const float* __restrict__ w1, const float* __restrict__ bb1,
        const float* __restrict__ w3, const float* __restrict__ bb3,
        const float* __restrict__ w6, const float* __restrict__ bb6,
        const float* __restrict__ w9, const float* __restrict__ bb9,
        float scale) {
    int idx = blockIdx.x * 256 + threadIdx.x;
    int d = idx & 63;
    int l = (idx >> 6) & 1023;
    int h = (idx >> 16) & 7;
    int b = idx >> 19;
    int g = (h << 10) + l;
    int rb = g >> 3;
    int cb = (g & 7) << 6;
    const float* Fb = F + (size_t)b * (1024 * 512);
    size_t ob = (size_t)((b * 8 + h) * 4) * 65536 + l * 64 + d;
    out[ob]             = (conv_gather<1>(Fb, rb, cb, d, w1) + bb1[0]) * scale;
    out[ob + 65536]     = (conv_gather<3>(Fb, rb, cb, d, w3) + bb3[0]) * scale;
    out[ob + 2 * 65536] = (conv_gather<6>(Fb, rb, cb, d, w6) + bb6[0]) * scale;
    out[ob + 3 * 65536] = (conv_gather<9>(Fb, rb, cb, d, w9) + bb9[0]) * scale;
}

// ------------- fused scores (4 GEMMs K=64) + softmax over p + q-partials
__global__ __launch_bounds__(256, 4) void scores_attn(const float* __restrict__ Qp,
                                                      const float* __restrict__ Kp,
                                                      float* __restrict__ part) {
    int bid = blockIdx.x;
    int xcd = bid & 7, j = bid >> 3;        // j in [0,1024)
    int bh  = xcd + 8 * (j >> 8);           // [0,32)
    int qk  = j & 255;
    int qt  = qk >> 4;
    int q0  = qt << 6;
    int k0  = (qk & 15) << 6;
    __shared__ float Aq[64][68];   // [kk][q]
    __shared__ float Bk[64][68];   // [kk][k]
    int tn = threadIdx.x & 15, tm = threadIdx.x >> 4;
    float acc[4][4][4];   // [p][i(q)][j(k)] — all indices compile-time constant
#pragma unroll
    for (int p = 0; p < 4; p++)
#pragma unroll
        for (int i = 0; i < 4; i++)
#pragma unroll
            for (int j2 = 0; j2 < 4; j2++) acc[p][i][j2] = 0.f;

#pragma unroll
    for (int p = 0; p < 4; p++) {
        const float* Ab = Qp + (size_t)(bh * 4 + p) * 65536 + (size_t)q0 * 64;
        const float* Bb = Kp + (size_t)(bh * 4 + p) * 65536 + (size_t)k0 * 64;
        __syncthreads();
#pragma unroll
        for (int r = 0; r < 4; r++) {
            int rl = tm + 16 * r;               // local q (for A) / k (for B)
            float4 va = *(const float4*)&Ab[(size_t)rl * 64 + 4 * tn];
            float4 vb = *(const float4*)&Bb[(size_t)rl * 64 + 4 * tn];
            float av[4] = {va.x, va.y, va.z, va.w};
            float bv[4] = {vb.x, vb.y, vb.z, vb.w};
#pragma unroll
            for (int x = 0; x < 4; x++) {
                int kk = 4 * tn + x;
                int sw = ((kk >> 3) & 3) << 2;
                Aq[kk][rl ^ sw] = av[x];
                Bk[kk][rl ^ sw] = bv[x];
            }
        }
        __syncthreads();
#pragma unroll
        for (int kk = 0; kk < 64; kk++) {
            int sw = ((kk >> 3) & 3) << 2;
            float4 a = *(const float4*)&Aq[kk][(tm * 4) ^ sw];
            float4 b = *(const float4*)&Bk[kk][(tn * 4) ^ sw];
            float av[4] = {a.x, a.y, a.z, a.w};
            float bv[4] = {b.x, b.y, b.z, b.w};
#pragma unroll
            for (int i = 0; i < 4; i++)
#pragma unroll
                for (int j2 = 0; j2 < 4; j2++) acc[p][i][j2] += av[i] * bv[j2];
        }
    }

    float qsum[4][4];     // [p][j]
#pragma unroll
    for (int p = 0; p < 4; p++)
#pragma unroll
        for (int j2 = 0; j2 < 4; j2++) qsum[p][j2] = 0.f;
#pragma unroll
    for (int i = 0; i < 4; i++)
#pragma unroll
        for (int j2 = 0; j2 < 4; j2++) {
            float s0 = acc[0][i][j2], s1 = acc[1][i][j2];
            float s2 = acc[2][i][j2], s3 = acc[3][i][j2];
            float m = fmaxf(fmaxf(s0, s1), fmaxf(s2, s3));
            float e0 = __expf(s0 - m), e1 = __expf(s1 - m);
            float e2 = __expf(s2 - m), e3 = __expf(s3 - m);
            float inv = __builtin_amdgcn_rcpf(e0 + e1 + e2 + e3);
            qsum[0][j2] += e0 * inv; qsum[1][j2] += e1 * inv;
            qsum[2][j2] += e2 * inv; qsum[3][j2] += e3 * inv;
        }

    __syncthreads();
    float* red = &Aq[0][0];   // stride 257 (==1 mod 32)
#pragma unroll
    for (int p = 0; p < 4; p++)
#pragma unroll
        for (int j2 = 0; j2 < 4; j2++)
            red[tm * 257 + p * 64 + tn * 4 + j2] = qsum[p][j2];
    __syncthreads();
    int pp = threadIdx.x >> 6, kk2 = threadIdx.x & 63;
    float s = 0.f;
#pragma unroll
    for (int tt = 0; tt < 16; tt++) s += red[tt * 257 + pp * 64 + kk2];
    part[((size_t)(bh * 4 + pp) * 16 + qt) * 1024 + k0 + kk2] = s;
}

// ------------- attn_out[bhp][k] = sum over 16 q-tiles of part[bhp][qt][k]
__global__ __launch_bounds__(256) void attn_reduce(const float* __restrict__ part,
                                                   float* __restrict__ attn_out) {
    int idx = blockIdx.x * 256 + threadIdx.x;   // [0, 131072)
    int bhp = idx >> 10, k = idx & 1023;
    const float* pb = part + (size_t)bhp * 16384 + k;
    float s = 0.f;
#pragma unroll
    for (int qt = 0; qt < 16; qt++) s += pb[qt * 1024];
    attn_out[idx] = s;
}

// ------------------------------- context[b,h,q,:] = colsum(V[b,h]) broadcast
__global__ __launch_bounds__(256) void context_kernel(const float* __restrict__ V,
                                                      float* __restrict__ out) {
    int bh = blockIdx.x;
    const float* Vb = V + (size_t)bh * 65536;
    __shared__ float part[4][64];
    __shared__ float colsum[64];
    int d = threadIdx.x & 63, grp = threadIdx.x >> 6;
    float s = 0.f;
    for (int r = grp; r < 1024; r += 4) s += Vb[r * 64 + d];
    part[grp][d] = s;
    __syncthreads();
    if (threadIdx.x < 64) colsum[d] = part[0][d] + part[1][d] + part[2][d] + part[3][d];
    __syncthreads();
    float val = colsum[d];
    float* ob = out + (size_t)bh * 65536;
    for (int q = grp; q < 1024; q += 4) ob[q * 64 + d] = val;
}

// ---------------------------------------------------------------------------
extern "C" void kernel_launch(void* const* d_in, const int* in_sizes, int n_in,
                              void* d_out, int out_size, void* d_ws, size_t ws_size,
                              hipStream_t stream) {
    if (n_in < 19) return;
    if ((size_t)ws_size < WS_FLOATS_NEEDED * sizeof(float)) return;
    const float* Q = (const float*)d_in[0];
    const float* K = (const float*)d_in[1];
    const float* V = (const float*)d_in[2];
    const float* wq[4] = {(const float*)d_in[3], (const float*)d_in[5],
                          (const float*)d_in[7], (const float*)d_in[9]};
    const float* bq[4] = {(const float*)d_in[4], (const float*)d_in[6],
                          (const float*)d_in[8], (const float*)d_in[10]};
    const float* wk[4] = {(const float*)d_in[11], (const float*)d_in[13],
                          (const float*)d_in[15], (const float*)d_in[17]};
    const float* bk[4] = {(const float*)d_in[12], (const float*)d_in[14],
                          (const float*)d_in[16], (const float*)d_in[18]};

    float* ws   = (float*)d_ws;
    float* TcQ  = ws;                    // 2097152
    float* TsQ  = ws + 2097152;
    float* TcK  = ws + 4194304;
    float* TsK  = ws + 6291456;
    float* P    = ws + 8388608;          // 10485760 (4 splits x 8 maps x 1024x320)
    float* F    = ws;                    // 4194304, overlays TcQ/TsQ (dead)
    float* Qp   = ws + 4194304;          // 8388608, overlays TcK/TsK + P-head
    float* Kp   = ws + 12582912;         // 8388608, overlays P-tail
    float* part = ws + 20971520;         // 2097152

    float* ctx      = (float*)d_out;
    float* attn_out = ctx + 2097152;

    // stage 1: row-DFT GEMMs, direct stores
    stage1_fused<<<1280, 256, 0, stream>>>(Q, K, TcQ, TsQ, TcK, TsK);

    // stage 2 v2: rotation-trig + 8x8 blocking + prefetch, K-split x4 partials
    stage2_fused<<<640, 256, 0, stream>>>(TcQ, TsQ, TcK, TsK, P);

    // combine 4 partials + fill cols 257..511 by conjugate symmetry
    combine_mirror<<<8192, 256, 0, stream>>>(P, F);

    // multi-scale conv gathers; SCALE folded into Qp
    conv_all<<<8192, 256, 0, stream>>>(F, Qp, wq[0], bq[0], wq[1], bq[1],
                                       wq[2], bq[2], wq[3], bq[3], SCALE);
    conv_all<<<8192, 256, 0, stream>>>(F + 2097152, Kp, wk[0], bk[0], wk[1], bk[1],
                                       wk[2], bk[2], wk[3], bk[3], 1.0f);

    // fused scores + softmax(p) + per-tile q-sums -> part (no atomics)
    scores_attn<<<8192, 256, 0, stream>>>(Qp, Kp, part);

    // reduce q-tile partials -> attn_out
    attn_reduce<<<512, 256, 0, stream>>>(part, attn_out);

    // context = colsum(V) broadcast over q
    context_kernel<<<32, 256, 0, stream>>>(V, ctx);
}